// Round 1
// baseline (1775.145 us; speedup 1.0000x reference)
//
#include <hip/hip_runtime.h>
#include <hip/hip_cooperative_groups.h>
#include <math.h>

namespace cg = cooperative_groups;

constexpr int cB = 8, cT = 2048, cDU = 512, cDM = 512, cDA = 256, cDF = 12, cL = 4;
constexpr float cEPS = 1e-6f;
constexpr float cSCALE = 16.0f;   // sqrt(DA)
constexpr float cGAMMA = 1.0f;

typedef unsigned short u16;
typedef unsigned char u8;
typedef u16 u16x8 __attribute__((ext_vector_type(8)));

// ---------------- workspace layout (float offsets) ----------------
constexpr size_t F_SB = 0;                 // sbias  B*T
constexpr size_t F_UN = F_SB + 16384;      // unorm2 B*T
constexpr size_t F_LG = F_UN + 16384;      // logits B*T
constexpr size_t F_Y  = F_LG + 16384;      // y (final, per stage) B*T
constexpr size_t F_PR = F_Y  + 16384;      // prev   B*T
constexpr size_t F_OV = F_PR + 16384;      // overlap B*T
constexpr size_t F_SP = F_OV + 16384;      // spread partials 4096 (B*512)
constexpr size_t F_QK = F_SP + 4096;       // qk  B*DU
constexpr size_t F_M0 = F_QK + 4096;       // memory buf 0
constexpr size_t F_M1 = F_M0 + 4096;       // memory buf 1
constexpr size_t F_C  = F_M1 + 4096;       // c_raw B*DU
constexpr size_t F_Z  = F_C  + 4096;       // z B*DU
constexpr size_t F_SC = F_Z  + 4096;       // scalars B*8
constexpr size_t F_A  = F_SC + 64;         // A = Wk^T @ Wq, 512x512
constexpr size_t F_END = F_A + 262144;
constexpr size_t U_OFFB   = F_END * 4;                       // bf16 u
constexpr size_t U_BYTES  = (size_t)cB * cT * cDU * 2;
constexpr size_t S8_OFFB  = U_OFFB + U_BYTES;                // u8 sim
constexpr size_t S8_BYTES = (size_t)cB * cT * cT;
constexpr size_t WS_NEED_U   = S8_OFFB;
constexpr size_t WS_NEED_ALL = S8_OFFB + S8_BYTES;
// scal: 0 ysum_clamped, 1 coverage, 2 entropy, 3 wsq, 6 csq

__device__ __forceinline__ float wave_sum(float v) {
#pragma unroll
  for (int o = 32; o; o >>= 1) v += __shfl_down(v, o);
  return v;   // valid on lane 0
}
__device__ __forceinline__ float wave_max(float v) {
#pragma unroll
  for (int o = 32; o; o >>= 1) v = fmaxf(v, __shfl_down(v, o));
  return v;   // valid on lane 0
}
__device__ __forceinline__ float blk_max(float v, float* red, int wv, int lane) {
  v = wave_max(v);
  __syncthreads();
  if (lane == 0) red[wv] = v;
  __syncthreads();
  return fmaxf(fmaxf(red[0], red[1]), fmaxf(red[2], red[3]));
}
__device__ __forceinline__ float blk_sum(float v, float* red, int wv, int lane) {
  v = wave_sum(v);
  __syncthreads();
  if (lane == 0) red[wv] = v;
  __syncthreads();
  return red[0] + red[1] + red[2] + red[3];
}
__device__ __forceinline__ u16 f2bf(float f) {
  unsigned u = __float_as_uint(f);
  return (u16)((u + 0x7fffu + ((u >> 16) & 1u)) >> 16);
}
__device__ __forceinline__ float bf2f(u16 h) { return __uint_as_float(((unsigned)h) << 16); }
__device__ __forceinline__ float dot4(float4 a, float4 b) {
  return a.x * b.x + a.y * b.y + a.z * b.z + a.w * b.w;
}
__device__ __forceinline__ unsigned pack4(float a, float b, float c, float d) {
  unsigned b0 = (unsigned)(a * 255.f + 0.5f);
  unsigned b1 = (unsigned)(b * 255.f + 0.5f);
  unsigned b2 = (unsigned)(c * 255.f + 0.5f);
  unsigned b3 = (unsigned)(d * 255.f + 0.5f);
  return b0 | (b1 << 8) | (b2 << 16) | (b3 << 24);
}
__device__ __forceinline__ void dotu8(float& sd, unsigned w, float4 p) {
  sd += (float)(w & 255u) * p.x + (float)((w >> 8) & 255u) * p.y +
        (float)((w >> 16) & 255u) * p.z + (float)(w >> 24) * p.w;
}

// ==== k_init: blocks 0..1023 mem0 copy + u->bf16 + sbias/unorm2; 1024..1087 A=Wk^T@Wq ==
__global__ __launch_bounds__(256) void k_init(
    const float* __restrict__ u, const float* __restrict__ sf,
    const float* __restrict__ mem0,
    const float* __restrict__ Wq, const float* __restrict__ Wk,
    const float* __restrict__ w1, const float* __restrict__ b1,
    const float* __restrict__ w2, const float* __restrict__ b2,
    float* __restrict__ wsf, u16* __restrict__ ubf, int use_ubf) {
  const int tid = threadIdx.x;
  if (blockIdx.x >= 1024) {
    // A[j,i] = sum_a Wk[a,j] * Wq[a,i];  block handles 8 j rows
    __shared__ float wkj[32][8];
    int j0 = (blockIdx.x - 1024) * 8;
    float acc[8][2] = {};
    for (int a0 = 0; a0 < cDA; a0 += 32) {
      wkj[tid >> 3][tid & 7] = Wk[(size_t)(a0 + (tid >> 3)) * cDU + j0 + (tid & 7)];
      __syncthreads();
#pragma unroll 8
      for (int aa = 0; aa < 32; ++aa) {
        float wq0 = Wq[(size_t)(a0 + aa) * cDM + tid * 2];
        float wq1 = Wq[(size_t)(a0 + aa) * cDM + tid * 2 + 1];
#pragma unroll
        for (int r = 0; r < 8; ++r) {
          acc[r][0] += wkj[aa][r] * wq0;
          acc[r][1] += wkj[aa][r] * wq1;
        }
      }
      __syncthreads();
    }
#pragma unroll
    for (int r = 0; r < 8; ++r) {
      wsf[F_A + (size_t)(j0 + r) * cDU + tid * 2] = acc[r][0];
      wsf[F_A + (size_t)(j0 + r) * cDU + tid * 2 + 1] = acc[r][1];
    }
    return;
  }
  const int gt = blockIdx.x * 256 + tid;
  const int nt = 1024 * 256;
  const int wv = tid >> 6, lane = tid & 63;
  const int gw = blockIdx.x * 4 + wv;
  const int nwv = 1024 * 4;

  for (int i = gt; i < cB * cDM; i += nt) wsf[F_M0 + i] = mem0[i];

  if (use_ubf) {
    const int NU8 = cB * cT * cDU / 8;
    const float4* src = (const float4*)u;
    for (int c = gt; c < NU8; c += nt) {
      float4 f0 = src[(size_t)c * 2], f1 = src[(size_t)c * 2 + 1];
      u16x8 o;
      o[0] = f2bf(f0.x); o[1] = f2bf(f0.y); o[2] = f2bf(f0.z); o[3] = f2bf(f0.w);
      o[4] = f2bf(f1.x); o[5] = f2bf(f1.y); o[6] = f2bf(f1.z); o[7] = f2bf(f1.w);
      *(u16x8*)(ubf + (size_t)c * 8) = o;
    }
  }
  for (int row = gw; row < cB * cT; row += nwv) {
    float d0 = sf[(size_t)row * cDF + 8];
    float d1 = sf[(size_t)row * cDF + 9];
    float d2 = sf[(size_t)row * cDF + 10];
    float acc = 0.f;
#pragma unroll
    for (int i = 0; i < 4; ++i) {
      int a = lane * 4 + i;
      float h = d0 * w1[a * 3 + 0] + d1 * w1[a * 3 + 1] + d2 * w1[a * 3 + 2] + b1[a];
      float g = 0.5f * h * (1.0f + erff(h * 0.70710678118654752f));
      acc += g * w2[a];
    }
    float un = 0.f;
    const float4* ur = (const float4*)(u + (size_t)row * cDU);
#pragma unroll
    for (int m = 0; m < 2; ++m) { float4 x = ur[lane + m * 64]; un += dot4(x, x); }
    acc = wave_sum(acc);
    un = wave_sum(un);
    if (lane == 0) { wsf[F_SB + row] = acc + b2[0]; wsf[F_UN + row] = un; }
  }
}

// ==== k_main: the whole 4-stage loop, one cooperative kernel, grid.sync between phases
__global__ __launch_bounds__(256, 4) void k_main(
    const float* __restrict__ u, const float* __restrict__ sim,
    const float* __restrict__ logt, const float* __restrict__ Wv,
    const float* __restrict__ W_ih, const float* __restrict__ b_ih,
    const float* __restrict__ W_hh, const float* __restrict__ b_hh,
    float* __restrict__ ws, u16* __restrict__ ubf, u8* __restrict__ sim8,
    float* __restrict__ out, int use_ubf, int use_s8) {
  cg::grid_group gg = cg::this_grid();
  __shared__ float lds[4104];          // [0..2175] ylds / [2048..4095] comb / [4096..4099] red
  float* red = lds + 4096;
  const int tid = threadIdx.x;
  const int wv = tid >> 6, lane = tid & 63;
  const int wid = blockIdx.x * 4 + wv;
  const int nw = gridDim.x * 4;

  const float temp = fminf(fmaxf(expf(logt[0]), 0.1f), 10.0f);

  for (int stage = 0; stage < cL; ++stage) {
    float* mcur = ws + ((stage & 1) ? F_M1 : F_M0);
    float* mnxt = ws + ((stage & 1) ? F_M0 : F_M1);
    const int convert = (stage == 0 && use_s8) ? 1 : 0;

    // ---------- phase A: qk = A @ mem, zero c_raw ----------
    {
      for (int t = wid; t < cB * cDM; t += nw) {
        int b = t >> 9, j = t & 511;
        const float4* ar = (const float4*)(ws + F_A + (size_t)j * cDM);
        const float4* mr = (const float4*)(mcur + (size_t)b * cDM);
        float acc = dot4(ar[lane * 2], mr[lane * 2]) + dot4(ar[lane * 2 + 1], mr[lane * 2 + 1]);
        acc = wave_sum(acc);
        if (lane == 0) ws[F_QK + t] = acc;
      }
      for (int t = blockIdx.x * 256 + tid; t < cB * cDU; t += gridDim.x * 256)
        ws[F_C + t] = 0.f;
    }
    gg.sync();

    // ---------- phase B: logits = (u.qk/SCALE + sbias - g*sim@prev)/temp ----------
    {
      for (int s = wid; s < 4096; s += nw) {
        const int b = s >> 9;
        const float4* qk4 = (const float4*)(ws + F_QK + (size_t)b * cDU);
        float4 q0 = qk4[lane * 2], q1 = qk4[lane * 2 + 1];
        float4 pv[8];
        if (stage > 0 && use_s8) {
          const float4* pr4 = (const float4*)(ws + F_PR + (size_t)b * cT);
#pragma unroll
          for (int m = 0; m < 2; ++m)
#pragma unroll
            for (int k = 0; k < 4; ++k) pv[m * 4 + k] = pr4[m * 256 + lane * 4 + k];
        }
#pragma unroll
        for (int i = 0; i < 4; ++i) {
          int grow = s * 4 + i;
          float acc;
          if (use_ubf) {
            u16x8 sv = *(const u16x8*)(ubf + (size_t)grow * cDU + lane * 8);
            acc = bf2f(sv[0]) * q0.x + bf2f(sv[1]) * q0.y + bf2f(sv[2]) * q0.z + bf2f(sv[3]) * q0.w +
                  bf2f(sv[4]) * q1.x + bf2f(sv[5]) * q1.y + bf2f(sv[6]) * q1.z + bf2f(sv[7]) * q1.w;
          } else {
            const float4* ur = (const float4*)(u + (size_t)grow * cDU);
            acc = dot4(ur[lane * 2], q0) + dot4(ur[lane * 2 + 1], q1);
          }
          acc *= (1.0f / cSCALE);
          if (stage > 0) {
            float sd = 0.f;
            if (use_s8) {
              const u8* sr = sim8 + (size_t)grow * cT;
              uint4 sq0 = *(const uint4*)(sr + lane * 16);
              uint4 sq1 = *(const uint4*)(sr + 1024 + lane * 16);
              dotu8(sd, sq0.x, pv[0]); dotu8(sd, sq0.y, pv[1]);
              dotu8(sd, sq0.z, pv[2]); dotu8(sd, sq0.w, pv[3]);
              dotu8(sd, sq1.x, pv[4]); dotu8(sd, sq1.y, pv[5]);
              dotu8(sd, sq1.z, pv[6]); dotu8(sd, sq1.w, pv[7]);
              sd *= (1.0f / 255.0f);
            } else {
              const float4* sr = (const float4*)(sim + (size_t)grow * cT);
              const float4* pr4 = (const float4*)(ws + F_PR + (size_t)b * cT);
#pragma unroll
              for (int m = 0; m < 8; ++m) sd += dot4(sr[lane + m * 64], pr4[lane + m * 64]);
            }
            acc -= cGAMMA * sd;
          }
          acc = wave_sum(acc);
          if (lane == 0) ws[F_LG + grow] = (acc + ws[F_SB + grow]) / temp;
        }
      }
    }
    gg.sync();

    // ---------- phase C: softmax(logits) + overlap = sim @ y1 (+stage-0 u8 convert) ----
    {
      for (int bx = blockIdx.x; bx < 1024; bx += gridDim.x) {
        const int b = bx >> 7;
        float l[8];
        float mx = -INFINITY;
#pragma unroll
        for (int e = 0; e < 8; ++e) { l[e] = ws[F_LG + b * cT + e * 256 + tid]; mx = fmaxf(mx, l[e]); }
        mx = blk_max(mx, red, wv, lane);
        float sum = 0.f;
#pragma unroll
        for (int e = 0; e < 8; ++e) {
          float ev = expf(l[e] - mx);
          sum += ev;
          int sidx = e * 256 + tid;
          lds[sidx + (sidx >> 4)] = ev;
        }
        sum = blk_sum(sum, red, wv, lane);
        float invS = 1.f / sum;
        for (int r = 0; r < 4; ++r) {
          int row = bx * 16 + wv * 4 + r;
          float acc = 0.f;
          if (use_s8 && !convert) {
            const u8* sr = sim8 + (size_t)row * cT;
#pragma unroll
            for (int m = 0; m < 2; ++m) {
              uint4 sq = *(const uint4*)(sr + m * 1024 + lane * 16);
              int s0 = m * 1024 + lane * 16;
#pragma unroll
              for (int k = 0; k < 4; ++k) {
                unsigned w = (&sq.x)[k];
                int si = s0 + k * 4;
                acc += (float)(w & 255u)         * lds[si + (si >> 4)] +
                       (float)((w >> 8) & 255u)  * lds[(si + 1) + ((si + 1) >> 4)] +
                       (float)((w >> 16) & 255u) * lds[(si + 2) + ((si + 2) >> 4)] +
                       (float)(w >> 24)          * lds[(si + 3) + ((si + 3) >> 4)];
              }
            }
            acc *= (1.0f / 255.0f);
          } else {
            const float4* sr = (const float4*)(sim + (size_t)row * cT);
#pragma unroll
            for (int m = 0; m < 2; ++m) {
              uint4 oq;
#pragma unroll
              for (int k = 0; k < 4; ++k) {
                float4 sv = sr[m * 256 + lane * 4 + k];
                int si = m * 1024 + lane * 16 + k * 4;
                acc += sv.x * lds[si + (si >> 4)] + sv.y * lds[(si + 1) + ((si + 1) >> 4)] +
                       sv.z * lds[(si + 2) + ((si + 2) >> 4)] + sv.w * lds[(si + 3) + ((si + 3) >> 4)];
                (&oq.x)[k] = pack4(sv.x, sv.y, sv.z, sv.w);
              }
              if (convert)
                *(uint4*)(sim8 + (size_t)row * cT + m * 1024 + lane * 16) = oq;
            }
          }
          acc = wave_sum(acc);
          if (lane == 0) ws[F_OV + row] = acc * invS;
        }
      }
    }
    gg.sync();

    // ---------- phase D: penalty + resoftmax + stats + centroid chunk accumulate ------
    {
      for (int bx = blockIdx.x; bx < 1024; bx += gridDim.x) {
        const int b = bx >> 7, ch = bx & 127;
        float o[8], l[8], yv8[8];
        float mo = -INFINITY;
#pragma unroll
        for (int e = 0; e < 8; ++e) { o[e] = ws[F_OV + b * cT + e * 256 + tid]; mo = fmaxf(mo, o[e]); }
        mo = fmaxf(blk_max(mo, red, wv, lane), cEPS);
        float ml = -INFINITY;
#pragma unroll
        for (int e = 0; e < 8; ++e) { l[e] = ws[F_LG + b * cT + e * 256 + tid] - o[e] / mo; ml = fmaxf(ml, l[e]); }
        ml = blk_max(ml, red, wv, lane);
        float sum = 0.f;
#pragma unroll
        for (int e = 0; e < 8; ++e) { l[e] = expf(l[e] - ml); sum += l[e]; }
        sum = blk_sum(sum, red, wv, lane);
        float inv = 1.f / sum;
        float ysr_p = 0.f, wsq_p = 0.f;
#pragma unroll
        for (int e = 0; e < 8; ++e) {
          yv8[e] = l[e] * inv;
          lds[e * 256 + tid] = yv8[e];
          ysr_p += yv8[e];
          wsq_p += yv8[e] * ws[F_UN + b * cT + e * 256 + tid];
        }
        float ysr = blk_sum(ysr_p, red, wv, lane);
        float ysc = fmaxf(ysr, cEPS);
        float wsq = blk_sum(wsq_p, red, wv, lane);
        float ent_p = 0.f;
#pragma unroll
        for (int e = 0; e < 8; ++e) {
          float yn = yv8[e] / ysc;
          ent_p -= yn * logf(fmaxf(yn, cEPS));
        }
        float ent = blk_sum(ent_p, red, wv, lane);
        if (ch == 0) {
#pragma unroll
          for (int e = 0; e < 8; ++e) {
            int idx = b * cT + e * 256 + tid;
            ws[F_Y + idx] = yv8[e];
            if (stage == 0) ws[F_PR + idx] = yv8[e]; else ws[F_PR + idx] += yv8[e];
          }
          if (tid == 0) {
            ws[F_SC + b * 8 + 0] = ysc;
            ws[F_SC + b * 8 + 1] = ysr / (float)cT;
            ws[F_SC + b * 8 + 2] = ent;
            ws[F_SC + b * 8 + 3] = wsq;
          }
        }
        float acc[8] = {};
        for (int i = 0; i < 4; ++i) {
          int r = ch * 16 + wv * 4 + i;
          float yvv = lds[r];
          int row = b * cT + r;
          if (use_ubf) {
            u16x8 s8v = *(const u16x8*)(ubf + (size_t)row * cDU + lane * 8);
#pragma unroll
            for (int e = 0; e < 8; ++e) acc[e] += yvv * bf2f(s8v[e]);
          } else {
            const float4* ur = (const float4*)(u + (size_t)row * cDU);
            float4 a0 = ur[lane * 2], a1 = ur[lane * 2 + 1];
            acc[0] += yvv * a0.x; acc[1] += yvv * a0.y; acc[2] += yvv * a0.z; acc[3] += yvv * a0.w;
            acc[4] += yvv * a1.x; acc[5] += yvv * a1.y; acc[6] += yvv * a1.z; acc[7] += yvv * a1.w;
          }
        }
        __syncthreads();
#pragma unroll
        for (int e = 0; e < 8; ++e) lds[2048 + wv * 512 + lane * 8 + e] = acc[e];
        __syncthreads();
        float s0 = lds[2048 + tid] + lds[2048 + 512 + tid] + lds[2048 + 1024 + tid] + lds[2048 + 1536 + tid];
        float s1 = lds[2048 + tid + 256] + lds[2048 + 512 + tid + 256] +
                   lds[2048 + 1024 + tid + 256] + lds[2048 + 1536 + tid + 256];
        atomicAdd(&ws[F_C + b * cDU + tid], s0);
        atomicAdd(&ws[F_C + b * cDU + tid + 256], s1);
      }
    }
    gg.sync();

    // ---------- phase E: z = Wv @ c_raw ; spread partials ----------
    {
      for (int t = wid; t < cB * cDU; t += nw) {
        int b = t >> 9, j = t & 511;
        const float4* c4 = (const float4*)(ws + F_C + (size_t)b * cDU);
        const float4* w4 = (const float4*)(Wv + (size_t)j * cDU);
        float acc = dot4(c4[lane * 2], w4[lane * 2]) + dot4(c4[lane * 2 + 1], w4[lane * 2 + 1]);
        acc = wave_sum(acc);
        if (lane == 0) ws[F_Z + t] = acc;
      }
      for (int s = wid; s < 4096; s += nw) {
        int b = s >> 9, loc = s & 511;
        float ysc = ws[F_SC + b * 8 + 0];
        float inv = 1.f / ysc;
        const float4* c4 = (const float4*)(ws + F_C + (size_t)b * cDU);
        float4 cr0 = c4[lane * 2], cr1 = c4[lane * 2 + 1];
        float4 cx0, cx1;
        cx0.x = cr0.x * inv; cx0.y = cr0.y * inv; cx0.z = cr0.z * inv; cx0.w = cr0.w * inv;
        cx1.x = cr1.x * inv; cx1.y = cr1.y * inv; cx1.z = cr1.z * inv; cx1.w = cr1.w * inv;
        float cen2 = wave_sum(dot4(cx0, cx0) + dot4(cx1, cx1));   // lane0-valid
        if (loc == 0) {
          float csq = wave_sum(dot4(cr0, cr0) + dot4(cr1, cr1));
          if (lane == 0) ws[F_SC + b * 8 + 6] = csq;
        }
        float part = 0.f;
        for (int i = 0; i < 4; ++i) {
          int row = b * cT + loc * 4 + i;
          float dot;
          if (use_ubf) {
            u16x8 sv = *(const u16x8*)(ubf + (size_t)row * cDU + lane * 8);
            dot = bf2f(sv[0]) * cx0.x + bf2f(sv[1]) * cx0.y + bf2f(sv[2]) * cx0.z + bf2f(sv[3]) * cx0.w +
                  bf2f(sv[4]) * cx1.x + bf2f(sv[5]) * cx1.y + bf2f(sv[6]) * cx1.z + bf2f(sv[7]) * cx1.w;
          } else {
            const float4* ur = (const float4*)(u + (size_t)row * cDU);
            dot = dot4(ur[lane * 2], cx0) + dot4(ur[lane * 2 + 1], cx1);
          }
          dot = wave_sum(dot);
          if (lane == 0) {
            float d2 = ws[F_UN + row] - 2.f * dot + cen2;
            part += ws[F_Y + row] * sqrtf(fmaxf(d2, 0.f));
          }
        }
        if (lane == 0) ws[F_SP + s] = part;
      }
    }
    gg.sync();

    // ---------- phase F: GRU gates + memory update + output ----------
    {
      for (int t = wid; t < cB * cDM; t += nw) {
        int b = t >> 9, i = t & 511;
        const float4* xz = (const float4*)(ws + F_Z + (size_t)b * cDU);
        const float4* xm = (const float4*)(mcur + (size_t)b * cDM);
        float4 z0 = xz[lane * 2], z1 = xz[lane * 2 + 1];
        float4 m0 = xm[lane * 2], m1 = xm[lane * 2 + 1];
        float ysc = ws[F_SC + b * 8 + 0];
        float sv_ = 0.f;
#pragma unroll
        for (int k2 = 0; k2 < 8; ++k2) sv_ += ws[F_SP + b * 512 + lane * 8 + k2];
        float spr_raw = wave_sum(sv_);
        float aI[3], aH[3];
#pragma unroll
        for (int g = 0; g < 3; ++g) {
          size_t rrow = (size_t)(g * 512 + i);
          const float4* wI = (const float4*)(W_ih + rrow * 516);
          float a = dot4(z0, wI[lane * 2]) + dot4(z1, wI[lane * 2 + 1]);
          if (lane == 0) {
            float4 wt = wI[128];
            float cov = ws[F_SC + b * 8 + 1], ent = ws[F_SC + b * 8 + 2];
            float spr = spr_raw / ysc;
            float cmp = 2.f * (ysc * ws[F_SC + b * 8 + 3] - ws[F_SC + b * 8 + 6]) / fmaxf(ysc * ysc, cEPS);
            a += cov * wt.x + ent * wt.y + spr * wt.z + cmp * wt.w;
          }
          aI[g] = wave_sum(a);
          const float4* wH = (const float4*)(W_hh + rrow * cDM);
          float h = dot4(m0, wH[lane * 2]) + dot4(m1, wH[lane * 2 + 1]);
          aH[g] = wave_sum(h);
        }
        if (lane == 0) {
          float gir = aI[0] + b_ih[i],        ghr = aH[0] + b_hh[i];
          float giz = aI[1] + b_ih[512 + i],  ghz = aH[1] + b_hh[512 + i];
          float gin = aI[2] + b_ih[1024 + i], ghn = aH[2] + b_hh[1024 + i];
          float rg = 1.f / (1.f + expf(-(gir + ghr)));
          float zg = 1.f / (1.f + expf(-(giz + ghz)));
          float ng = tanhf(gin + rg * ghn);
          float mold = mcur[b * cDM + i];
          mnxt[b * cDM + i] = (1.f - zg) * ng + zg * mold;
          out[(size_t)(b * cL + stage) * cDU + i] = ws[F_Z + b * cDU + i];
        }
      }
    }
    if (stage < cL - 1) gg.sync();
  }
}

extern "C" void kernel_launch(void* const* d_in, const int* in_sizes, int n_in,
                              void* d_out, int out_size, void* d_ws, size_t ws_size,
                              hipStream_t stream) {
  const float* u    = (const float*)d_in[0];
  const float* sf   = (const float*)d_in[1];
  const float* sim  = (const float*)d_in[2];
  const float* mem0 = (const float*)d_in[3];
  const float* Wq   = (const float*)d_in[4];
  const float* Wk   = (const float*)d_in[5];
  const float* Wv   = (const float*)d_in[6];
  const float* sbw1 = (const float*)d_in[7];
  const float* sbb1 = (const float*)d_in[8];
  const float* sbw2 = (const float*)d_in[9];
  const float* sbb2 = (const float*)d_in[10];
  const float* logt = (const float*)d_in[11];
  const float* W_ih = (const float*)d_in[12];
  const float* b_ih = (const float*)d_in[13];
  const float* W_hh = (const float*)d_in[14];
  const float* b_hh = (const float*)d_in[15];
  float* out = (float*)d_out;
  float* ws  = (float*)d_ws;
  u16* ubf  = (u16*)((char*)d_ws + U_OFFB);
  u8* sim8  = (u8*)((char*)d_ws + S8_OFFB);

  int use_ubf = (ws_size >= WS_NEED_U) ? 1 : 0;
  int use_s8  = (ws_size >= WS_NEED_ALL) ? 1 : 0;

  k_init<<<1088, 256, 0, stream>>>(u, sf, mem0, Wq, Wk, sbw1, sbb1, sbw2, sbb2,
                                   ws, ubf, use_ubf);

  // Cooperative grid size: query once; mappings are grid-stride so any size is correct.
  static int nblk = 0;
  if (nblk == 0) {
    int occ = 0;
    if (hipOccupancyMaxActiveBlocksPerMultiprocessor(&occ, (const void*)k_main, 256, 0) != hipSuccess || occ <= 0)
      occ = 1;
    nblk = occ * 256;              // 256 CUs on MI355X
    if (nblk > 1024) nblk = 1024;
    if (nblk < 256) nblk = 256;
  }
  void* kargs[] = {(void*)&u, (void*)&sim, (void*)&logt, (void*)&Wv,
                   (void*)&W_ih, (void*)&b_ih, (void*)&W_hh, (void*)&b_hh,
                   (void*)&ws, (void*)&ubf, (void*)&sim8, (void*)&out,
                   (void*)&use_ubf, (void*)&use_s8};
  hipLaunchCooperativeKernel((const void*)k_main, dim3(nblk), dim3(256), kargs, 0, stream);
}